// Round 3
// baseline (364.344 us; speedup 1.0000x reference)
//
#include <hip/hip_runtime.h>

typedef __attribute__((ext_vector_type(8))) short bf16x8;
typedef __attribute__((ext_vector_type(4))) float f32x4;

static constexpr int HH = 224, WW = 224;
static constexpr int HP = 226, WP = 226;
static constexpr size_t XH_ELEMS = (size_t)8 * HP * WP * 64;       // 26,153,216 ushorts
static constexpr size_t WS_NEED = 2 * (XH_ELEMS + 9 * 64 * 64 + 64 * 64);

__device__ __forceinline__ ushort f2bf(float f) {
    unsigned u = __builtin_bit_cast(unsigned, f);
    u += 0x7FFFu + ((u >> 16) & 1u);   // round-to-nearest-even
    return (ushort)(u >> 16);
}

// ---- weight reorder: w1r[ch][n][c] bf16 (ch=dy*3+dx), w2r[o][c] bf16
__global__ void prep_w(const float* __restrict__ W1, const float* __restrict__ W2,
                       ushort* __restrict__ w1r, ushort* __restrict__ w2r) {
    const int idx = blockIdx.x * 256 + threadIdx.x;
    if (idx < 36864) {
        const int ch = idx >> 12, n = (idx >> 6) & 63, c = idx & 63;
        w1r[idx] = f2bf(W1[n * 576 + c * 9 + ch]);
    } else if (idx < 40960) {
        const int j = idx - 36864;
        w2r[j] = f2bf(W2[j]);
    }
}

// ---- zero the 1-px border of xh (padded NHWC layout)
__global__ void prep_border(ushort* __restrict__ xh) {
    const int t = blockIdx.x * 256 + threadIdx.x;   // < 57600
    const int b = t / 7200, r = t - b * 7200;
    const int slot = r >> 3, cg = r & 7;
    int yp, p;
    if (slot < 226)      { yp = 0;   p = slot; }
    else if (slot < 452) { yp = 225; p = slot - 226; }
    else if (slot < 676) { p = 0;    yp = slot - 452 + 1; }
    else                 { p = 225;  yp = slot - 676 + 1; }
    bf16x8 z = {0, 0, 0, 0, 0, 0, 0, 0};
    *reinterpret_cast<bf16x8*>(xh + (((size_t)b * HP + yp) * WP + p) * 64 + cg * 8) = z;
}

// ---- x transpose: NCHW fp32 -> padded NHWC bf16. One block per (gy, b) row.
__global__ __launch_bounds__(256)
void prep_x(const float* __restrict__ x, ushort* __restrict__ xh) {
    __shared__ ushort row[224 * 72];   // [px][c], halfword stride 72 (16B-aligned rows)
    const int gy = blockIdx.x, b = blockIdx.y;
    const float* xg = x + ((size_t)b * 64 * HH + gy) * WW;
    for (int e = threadIdx.x; e < 3584; e += 256) {   // 64 ch x 56 float4
        const int c = e & 63;
        const int x4 = (e >> 6) * 4;
        const float4 v = *reinterpret_cast<const float4*>(xg + (size_t)c * HH * WW + x4);
        row[(x4 + 0) * 72 + c] = f2bf(v.x);
        row[(x4 + 1) * 72 + c] = f2bf(v.y);
        row[(x4 + 2) * 72 + c] = f2bf(v.z);
        row[(x4 + 3) * 72 + c] = f2bf(v.w);
    }
    __syncthreads();
    ushort* dst = xh + (((size_t)b * HP + gy + 1) * WP + 1) * 64;
    for (int e = threadIdx.x; e < 1792; e += 256) {   // 224 px x 8 cgroups, 16B each
        const int p = e >> 3, cg = e & 7;
        const bf16x8 v = *reinterpret_cast<const bf16x8*>(&row[p * 72 + cg * 8]);
        *reinterpret_cast<bf16x8*>(dst + p * 64 + cg * 8) = v;
    }
}

// ---- main: barrier-free. Tile 8x32 px, 4 waves x (64 px x 64 hid). A-frags direct
// from padded NHWC xh (global), B-frags from w1r (L1-hot: shared by all waves/blocks).
__global__ __launch_bounds__(256, 4)
void mlpconv_main(const ushort* __restrict__ xh, const ushort* __restrict__ w1r,
                  const float* __restrict__ b1, const ushort* __restrict__ w2r,
                  const float* __restrict__ b2, float* __restrict__ out) {
    __shared__ ushort hs[4 * 16 * 72];   // per-wave h scratch only (9,216 B)

    const int tid = threadIdx.x;
    const int wave = tid >> 6, lane = tid & 63, l15 = lane & 15, quad = lane >> 4;
    const int x0 = blockIdx.x * 32, y0 = blockIdx.y * 8, b = blockIdx.z;
    const int ko = quad * 8;

    // per-lane bases; all loop offsets are compile-time constants
    const ushort* a0 = xh + (((size_t)b * HP + y0 + 2 * wave) * WP + x0 + l15) * 64 + ko;
    const ushort* w1b = w1r + l15 * 64 + ko;

    float b1v[4];
    #pragma unroll
    for (int nt = 0; nt < 4; ++nt) b1v[nt] = b1[nt * 16 + l15];

    f32x4 acc[4][4];   // C layout: col=lane&15 (=n), row=quad*4+reg (=m)
    #pragma unroll
    for (int mt = 0; mt < 4; ++mt)
        #pragma unroll
        for (int nt = 0; nt < 4; ++nt)
            acc[mt][nt] = (f32x4){b1v[nt], b1v[nt], b1v[nt], b1v[nt]};

    #pragma unroll
    for (int ch = 0; ch < 9; ++ch) {
        const int dy = ch / 3, dx = ch - 3 * (ch / 3);
        #pragma unroll
        for (int s = 0; s < 2; ++s) {
            bf16x8 bfr[4];
            #pragma unroll
            for (int nt = 0; nt < 4; ++nt)
                bfr[nt] = *reinterpret_cast<const bf16x8*>(
                    w1b + ch * 4096 + nt * 1024 + s * 32);
            #pragma unroll
            for (int mt = 0; mt < 4; ++mt) {
                const bf16x8 afr = *reinterpret_cast<const bf16x8*>(
                    a0 + (((mt >> 1) + dy) * WP + (mt & 1) * 16 + dx) * 64 + s * 32);
                #pragma unroll
                for (int nt = 0; nt < 4; ++nt)
                    acc[mt][nt] = __builtin_amdgcn_mfma_f32_16x16x32_bf16(
                        afr, bfr[nt], acc[mt][nt], 0, 0, 0);
            }
        }
    }

    // ---- epilogue: ReLU -> bf16 h (per-wave LDS, no barrier) -> GEMM2 -> +b2 -> store
    float4 b2q[4];
    #pragma unroll
    for (int it = 0; it < 4; ++it)
        b2q[it] = *reinterpret_cast<const float4*>(b2 + it * 16 + quad * 4);

    bf16x8 wa2[2][4];
    #pragma unroll
    for (int k2 = 0; k2 < 2; ++k2)
        #pragma unroll
        for (int it = 0; it < 4; ++it)
            wa2[k2][it] = *reinterpret_cast<const bf16x8*>(
                w2r + (it * 16 + l15) * 64 + k2 * 32 + quad * 8);

    ushort* myh = &hs[wave * (16 * 72)];
    float* outg = out + (size_t)b * (64 * HH * WW);

    #pragma unroll
    for (int mt = 0; mt < 4; ++mt) {
        #pragma unroll
        for (int ni = 0; ni < 4; ++ni)
            #pragma unroll
            for (int r = 0; r < 4; ++r) {
                float v = acc[mt][ni][r];
                v = v > 0.f ? v : 0.f;
                myh[(quad * 4 + r) * 72 + ni * 16 + l15] = f2bf(v);
            }
        f32x4 acc2[4];   // D2: col=lane&15 (=px), row=quad*4+reg (=cout)
        #pragma unroll
        for (int it = 0; it < 4; ++it)
            acc2[it] = (f32x4){b2q[it].x, b2q[it].y, b2q[it].z, b2q[it].w};
        #pragma unroll
        for (int k2 = 0; k2 < 2; ++k2) {
            const bf16x8 hb = *reinterpret_cast<const bf16x8*>(
                &myh[l15 * 72 + k2 * 32 + quad * 8]);
            #pragma unroll
            for (int it = 0; it < 4; ++it)
                acc2[it] = __builtin_amdgcn_mfma_f32_16x16x32_bf16(
                    wa2[k2][it], hb, acc2[it], 0, 0, 0);
        }
        const int gy = y0 + 2 * wave + (mt >> 1);
        const int gx = x0 + (mt & 1) * 16 + l15;
        #pragma unroll
        for (int it = 0; it < 4; ++it)
            #pragma unroll
            for (int r = 0; r < 4; ++r) {
                const int o = it * 16 + quad * 4 + r;
                outg[(o * HH + gy) * WW + gx] = acc2[it][r];
            }
    }
}

// ================= fallback (R2 structure, 80 KB ws) =================
__global__ __launch_bounds__(256, 3)
void mlpconv_fallback(const float* __restrict__ xin, const ushort* __restrict__ w1r,
                      const float* __restrict__ b1, const ushort* __restrict__ w2r,
                      const float* __restrict__ b2, float* __restrict__ out) {
    __shared__ ushort xs[10 * 40 * 64];
    const int tid = threadIdx.x;
    const int wave = tid >> 6, lane = tid & 63, l15 = lane & 15, quad = lane >> 4;
    const int x0 = blockIdx.x * 32, y0 = blockIdx.y * 8, b = blockIdx.z;
    const float* xg = xin + (size_t)b * (64 * HH * WW);
    for (int e = tid; e < 6400; e += 256) {
        const int i = e % 10, t = e / 10, c = t & 63, r = t >> 6;
        const int gy = y0 + r - 1, gx4 = x0 - 4 + i * 4;
        float4 v = make_float4(0.f, 0.f, 0.f, 0.f);
        if (((unsigned)gy < (unsigned)HH) && ((unsigned)gx4 <= 220u))
            v = *reinterpret_cast<const float4*>(xg + ((size_t)c * HH + gy) * WW + gx4);
        const int p0 = r * 40 + i * 4;
        xs[(p0 + 0) * 64 + (c ^ (((p0 + 0) & 7) * 8))] = f2bf(v.x);
        xs[(p0 + 1) * 64 + (c ^ (((p0 + 1) & 7) * 8))] = f2bf(v.y);
        xs[(p0 + 2) * 64 + (c ^ (((p0 + 2) & 7) * 8))] = f2bf(v.z);
        xs[(p0 + 3) * 64 + (c ^ (((p0 + 3) & 7) * 8))] = f2bf(v.w);
    }
    float b1v[4];
    #pragma unroll
    for (int nt = 0; nt < 4; ++nt) b1v[nt] = b1[nt * 16 + l15];
    f32x4 acc[4][4];
    #pragma unroll
    for (int mt = 0; mt < 4; ++mt)
        #pragma unroll
        for (int nt = 0; nt < 4; ++nt)
            acc[mt][nt] = (f32x4){b1v[nt], b1v[nt], b1v[nt], b1v[nt]};
    __syncthreads();
    #pragma unroll 2
    for (int ks = 0; ks < 18; ++ks) {
        const int ch = ks >> 1, s = ks & 1;
        const int dy = ch / 3, dx = ch - 3 * (ch / 3);
        const int ko = s * 32 + quad * 8;
        bf16x8 bfr[4];
        #pragma unroll
        for (int nt = 0; nt < 4; ++nt)
            bfr[nt] = *reinterpret_cast<const bf16x8*>(
                w1r + ch * 4096 + (nt * 16 + l15) * 64 + ko);
        const int kswz = ko ^ (((l15 + dx + 3) & 7) * 8);
        #pragma unroll
        for (int mt = 0; mt < 4; ++mt) {
            const int row = 2 * wave + (mt >> 1) + dy;
            const int col = (mt & 1) * 16 + l15 + dx + 3;
            const bf16x8 afr = *reinterpret_cast<const bf16x8*>(
                &xs[(row * 40 + col) * 64 + kswz]);
            #pragma unroll
            for (int nt = 0; nt < 4; ++nt)
                acc[mt][nt] = __builtin_amdgcn_mfma_f32_16x16x32_bf16(
                    afr, bfr[nt], acc[mt][nt], 0, 0, 0);
        }
    }
    __syncthreads();
    float4 b2q[4];
    #pragma unroll
    for (int it = 0; it < 4; ++it)
        b2q[it] = *reinterpret_cast<const float4*>(b2 + it * 16 + quad * 4);
    bf16x8 wa2[2][4];
    #pragma unroll
    for (int k2 = 0; k2 < 2; ++k2)
        #pragma unroll
        for (int it = 0; it < 4; ++it)
            wa2[k2][it] = *reinterpret_cast<const bf16x8*>(
                w2r + (it * 16 + l15) * 64 + k2 * 32 + quad * 8);
    ushort* myh = &xs[wave * (16 * 72)];
    float* outg = out + (size_t)b * (64 * HH * WW);
    #pragma unroll
    for (int mt = 0; mt < 4; ++mt) {
        #pragma unroll
        for (int ni = 0; ni < 4; ++ni)
            #pragma unroll
            for (int r = 0; r < 4; ++r) {
                float v = acc[mt][ni][r];
                v = v > 0.f ? v : 0.f;
                myh[(quad * 4 + r) * 72 + ni * 16 + l15] = f2bf(v);
            }
        f32x4 acc2[4];
        #pragma unroll
        for (int it = 0; it < 4; ++it)
            acc2[it] = (f32x4){b2q[it].x, b2q[it].y, b2q[it].z, b2q[it].w};
        #pragma unroll
        for (int k2 = 0; k2 < 2; ++k2) {
            const bf16x8 hb = *reinterpret_cast<const bf16x8*>(
                &myh[l15 * 72 + k2 * 32 + quad * 8]);
            #pragma unroll
            for (int it = 0; it < 4; ++it)
                acc2[it] = __builtin_amdgcn_mfma_f32_16x16x32_bf16(
                    wa2[k2][it], hb, acc2[it], 0, 0, 0);
        }
        const int gy = y0 + 2 * wave + (mt >> 1);
        const int gx = x0 + (mt & 1) * 16 + l15;
        #pragma unroll
        for (int it = 0; it < 4; ++it)
            #pragma unroll
            for (int r = 0; r < 4; ++r) {
                const int o = it * 16 + quad * 4 + r;
                outg[(o * HH + gy) * WW + gx] = acc2[it][r];
            }
    }
}

extern "C" void kernel_launch(void* const* d_in, const int* in_sizes, int n_in,
                              void* d_out, int out_size, void* d_ws, size_t ws_size,
                              hipStream_t stream) {
    const float* x  = (const float*)d_in[0];
    const float* W1 = (const float*)d_in[1];
    const float* b1 = (const float*)d_in[2];
    const float* W2 = (const float*)d_in[3];
    const float* b2 = (const float*)d_in[4];
    float* out = (float*)d_out;

    if (ws_size >= WS_NEED) {
        ushort* xh  = (ushort*)d_ws;
        ushort* w1r = xh + XH_ELEMS;
        ushort* w2r = w1r + 9 * 64 * 64;
        prep_w<<<160, 256, 0, stream>>>(W1, W2, w1r, w2r);
        prep_border<<<225, 256, 0, stream>>>(xh);
        prep_x<<<dim3(HH, 8), 256, 0, stream>>>(x, xh);
        dim3 grid(WW / 32, HH / 8, 8);
        mlpconv_main<<<grid, dim3(256), 0, stream>>>(xh, w1r, b1, w2r, b2, out);
    } else {
        ushort* w1r = (ushort*)d_ws;
        ushort* w2r = w1r + 9 * 64 * 64;
        prep_w<<<160, 256, 0, stream>>>(W1, W2, w1r, w2r);
        dim3 grid(WW / 32, HH / 8, 8);
        mlpconv_fallback<<<grid, dim3(256), 0, stream>>>(x, w1r, b1, w2r, b2, out);
    }
}